// Round 1
// 270.688 us; speedup vs baseline: 1.0617x; 1.0617x over previous
//
#include <hip/hip_runtime.h>
#include <stdint.h>

#define N_NODES 100000
#define N_EDGES 1600000
#define FDIM 128
#define NREL 50
#define BN_EPS 1e-3f
#define N_PAD 100096
#define NBUCK 782          // ceil(N_NODES / 128)
#define EPB 8192           // edges per ingest block
#define NBLK 196           // ceil(N_EDGES / EPB)
#define HBLK 6250          // N*32 / 512  (BN float4 blocks)
#define LEDCAP 2816        // max edges per bucket (mean 2046, sigma ~45 -> 17 sigma headroom)
#define SCAP 3712          // bucket stride in entries (= LEDCAP + 128*7 pad slack), mult of 8
#define NSG 1563           // ceil(N_NODES / 64)

typedef short short8_t __attribute__((ext_vector_type(8)));
typedef float f32x4_t __attribute__((ext_vector_type(4)));

__device__ __forceinline__ uint32_t f2bf(float f) {
    union { float f; uint32_t u; } v; v.f = f;
    uint32_t u = v.u;
    return (u + 0x7FFFu + ((u >> 16) & 1u)) >> 16;   // RNE, inputs finite
}
__device__ __forceinline__ float bflo(uint32_t p) {
    union { uint32_t u; float f; } v; v.u = p << 16; return v.f;
}
__device__ __forceinline__ float bfhi(uint32_t p) {
    union { uint32_t u; float f; } v; v.u = p & 0xFFFF0000u; return v.f;
}

// ---- fused prologue:
//   blocks [0,NBLK)          : edge binning (LDS hist -> one global atomicAdd per
//                              bucket reserves space in fixed-stride region -> scatter)
//   block NBLK               : WT cast (bf16 transpose of dense kernel)
//   blocks (NBLK,NBLK+HBLK]  : BN h (bf16x2-packed), params L2-hot
__global__ __launch_bounds__(512) void pre_kernel(
        const float* __restrict__ x, const int* __restrict__ rows,
        const int* __restrict__ cols, const float* __restrict__ vals,
        const int* __restrict__ rels, const float* __restrict__ relc,
        const float* __restrict__ gamma, const float* __restrict__ beta,
        const float* __restrict__ mean, const float* __restrict__ var,
        const float* __restrict__ W,
        uint2* __restrict__ h, uint16_t* __restrict__ WT,
        int* __restrict__ gcur, uint2* __restrict__ staging) {
    __shared__ int lh[NBUCK];
    __shared__ float lrel[NREL];
    int b = blockIdx.x, t = threadIdx.x;
    if (b < NBLK) {
        if (t < NREL) lrel[t] = 1.0f / (relc[t] + 1.0f);
        for (int i = t; i < NBUCK; i += 512) lh[i] = 0;
        __syncthreads();
        int e0 = b * EPB, e1 = min(e0 + EPB, N_EDGES);
        for (int e = e0 + t; e < e1; e += 512)
            atomicAdd(&lh[rows[e] >> 7], 1);
        __syncthreads();
        for (int i = t; i < NBUCK; i += 512) {
            int c = lh[i];
            int base = c ? atomicAdd(&gcur[i], c) : 0;
            lh[i] = i * SCAP + base;           // absolute cursor into staging
        }
        __syncthreads();
        for (int e = e0 + t; e < e1; e += 512) {
            int r = rows[e];
            float w = vals[e] * lrel[rels[e]];
            int p = atomicAdd(&lh[r >> 7], 1);
            uint2 s;
            s.x = (uint32_t)cols[e] | ((uint32_t)(r & 127) << 20);  // col<2^17
            s.y = __float_as_uint(w);
            staging[p] = s;
        }
    } else if (b == NBLK) {
        for (int idx = t; idx < FDIM * FDIM; idx += 512) {
            int f = idx >> 7, k = idx & 127;
            WT[idx] = (uint16_t)f2bf(W[k * FDIM + f]);   // WT[f][k]
        }
    } else {
        int i4 = (b - NBLK - 1) * 512 + t;     // 0 .. N*32-1 exactly
        int cg = (i4 & 31) * 4;
        float4 xv = ((const float4*)x)[i4];
        float4 g4 = *(const float4*)(gamma + cg);
        float4 b4 = *(const float4*)(beta + cg);
        float4 m4 = *(const float4*)(mean + cg);
        float4 v4 = *(const float4*)(var + cg);
        float s0 = g4.x * rsqrtf(v4.x + BN_EPS);
        float s1 = g4.y * rsqrtf(v4.y + BN_EPS);
        float s2 = g4.z * rsqrtf(v4.z + BN_EPS);
        float s3 = g4.w * rsqrtf(v4.w + BN_EPS);
        uint2 o;
        o.x = f2bf((xv.x - m4.x) * s0 + b4.x) | (f2bf((xv.y - m4.y) * s1 + b4.y) << 16);
        o.y = f2bf((xv.z - m4.z) * s2 + b4.z) | (f2bf((xv.w - m4.w) * s3 + b4.w) << 16);
        h[i4] = o;
    }
}

// ---- per-bucket: LDS-buffered in-place rewrite of staging into padded per-row
//      layout (pad to 8 for the 8-wide spmm loop) + rowrange ----
__global__ __launch_bounds__(256) void bucket_kernel(
        const int* __restrict__ gcur, uint2* __restrict__ staging,
        uint2* __restrict__ rowrange) {
    __shared__ uint2 led[LEDCAP];            // 22.5 KB edge buffer
    __shared__ int lh[128];
    __shared__ int sm[128];
    __shared__ int lcur[128];
    int b = blockIdx.x, r0 = b << 7, t = threadIdx.x;
    int nrows = min(128, N_NODES - r0);
    int cnt = min(gcur[b], LEDCAP);
    uint2* sg = staging + (size_t)b * SCAP;
    if (t < 128) lh[t] = 0;
    __syncthreads();
    for (int e = t; e < cnt; e += 256) {
        uint2 s = sg[e];
        led[e] = s;
        atomicAdd(&lh[(s.x >> 20) & 127], 1);
    }
    __syncthreads();
    int v = (t < 128) ? lh[t] : 0;
    int pv = (v + 7) & ~7;                   // pad each row to multiple of 8
    if (t < 128) sm[t] = pv;
    __syncthreads();
    for (int off = 1; off < 128; off <<= 1) {
        int xv = 0;
        if (t < 128 && t >= off) xv = sm[t - off];
        __syncthreads();
        if (t < 128) sm[t] += xv;
        __syncthreads();
    }
    int sbase = b * SCAP;
    int start = 0;
    if (t < 128) {
        start = sbase + sm[t] - pv;          // exclusive padded offset (mult of 8)
        lcur[t] = start;
        if (t < nrows) {
            uint2 rr; rr.x = (uint32_t)start; rr.y = (uint32_t)(start + pv);
            rowrange[r0 + t] = rr;
        }
    }
    __syncthreads();
    for (int e = t; e < cnt; e += 256) {
        uint2 s = led[e];
        int rl = (s.x >> 20) & 127;
        int p = atomicAdd(&lcur[rl], 1);
        uint2 o; o.x = s.x & 0xFFFFF; o.y = s.y;
        staging[p] = o;
    }
    // zero-weight pads: [start+v, start+pv) disjoint from reorder writes
    if (t < 128) {
        uint2 z; z.x = 0; z.y = 0;
        for (int k = v; k < pv; ++k) staging[start + k] = z;
    }
}

// ---- fused pull-SpMM + diag + GEMM: block = 64 rows, wave = 16 rows.
//      Phase 1: gather-accumulate (8 edges in flight), pack bf16 into
//      bank-swizzled LDS tile. Phase 2: MFMA m-tile straight from LDS. ----
__global__ __launch_bounds__(256, 6) void sg_kernel(
        const uint32_t* __restrict__ h, const uint2* __restrict__ rowrange,
        const uint2* __restrict__ scolw, const float* __restrict__ ck,
        const uint16_t* __restrict__ WT, const float* __restrict__ bias,
        float* __restrict__ out) {
    __shared__ uint32_t lp[64 * 64];         // 16 KB, word ^= (row&7)<<2 swizzle
    int wv = threadIdx.x >> 6;
    int lane = threadIdx.x & 63;
    int row0 = blockIdx.x * 64;

    // phase 1: this wave owns rows row0 + wv*16 .. +15
    for (int ri = 0; ri < 16; ++ri) {
        int rl = wv * 16 + ri;
        int row = row0 + rl;
        float ax = 0.f, ay = 0.f;
        if (row < N_NODES) {
            uint2 rg = rowrange[row];
            int e  = __builtin_amdgcn_readfirstlane((int)rg.x);
            int e1 = __builtin_amdgcn_readfirstlane((int)rg.y);
            uint32_t p = h[(uint32_t)row * 64u + lane];
            float coef = ck[row] + 1.0f;
            ax = coef * bflo(p);
            ay = coef * bfhi(p);
            for (; e < e1; e += 8) {
                const uint4* ep = (const uint4*)(scolw + e);   // 64B aligned
                uint4 eA = ep[0], eB = ep[1], eC = ep[2], eD = ep[3];
                uint32_t q0 = h[eA.x * 64u + lane];
                uint32_t q1 = h[eA.z * 64u + lane];
                uint32_t q2 = h[eB.x * 64u + lane];
                uint32_t q3 = h[eB.z * 64u + lane];
                uint32_t q4 = h[eC.x * 64u + lane];
                uint32_t q5 = h[eC.z * 64u + lane];
                uint32_t q6 = h[eD.x * 64u + lane];
                uint32_t q7 = h[eD.z * 64u + lane];
                float w0 = __uint_as_float(eA.y), w1 = __uint_as_float(eA.w);
                float w2 = __uint_as_float(eB.y), w3 = __uint_as_float(eB.w);
                float w4 = __uint_as_float(eC.y), w5 = __uint_as_float(eC.w);
                float w6 = __uint_as_float(eD.y), w7 = __uint_as_float(eD.w);
                ax += w0 * bflo(q0); ay += w0 * bfhi(q0);
                ax += w1 * bflo(q1); ay += w1 * bfhi(q1);
                ax += w2 * bflo(q2); ay += w2 * bfhi(q2);
                ax += w3 * bflo(q3); ay += w3 * bfhi(q3);
                ax += w4 * bflo(q4); ay += w4 * bfhi(q4);
                ax += w5 * bflo(q5); ay += w5 * bfhi(q5);
                ax += w6 * bflo(q6); ay += w6 * bfhi(q6);
                ax += w7 * bflo(q7); ay += w7 * bfhi(q7);
            }
        }
        uint32_t pk = f2bf(ax) | (f2bf(ay) << 16);
        lp[rl * 64 + (lane ^ ((rl & 7) << 2))] = pk;
    }
    __syncthreads();

    // phase 2: wave's own 16-row m-tile (rows row0 + wv*16 .. +15)
    int m = lane & 15, q = lane >> 4;
    int rowm = wv * 16 + m;
    short8_t a[4];
#pragma unroll
    for (int t = 0; t < 4; ++t) {
        int w0 = (q * 4 + t * 16) ^ ((rowm & 7) << 2);
        a[t] = *(const short8_t*)&lp[rowm * 64 + w0];
    }
    int row0m = row0 + wv * 16;
    for (int ct = 0; ct < 8; ++ct) {
        int col0 = ct * 16;
        const uint16_t* brow = WT + (size_t)(col0 + m) * FDIM + q * 8;
        f32x4_t acc = {0.f, 0.f, 0.f, 0.f};
#pragma unroll
        for (int t = 0; t < 4; ++t) {
            short8_t bb = *(const short8_t*)(brow + t * 32);
            acc = __builtin_amdgcn_mfma_f32_16x16x32_bf16(a[t], bb, acc, 0, 0, 0);
        }
        float bs = bias[col0 + m];
#pragma unroll
        for (int r = 0; r < 4; ++r) {
            int row = row0m + q * 4 + r;
            if (row < N_NODES)
                out[(size_t)row * FDIM + col0 + m] = acc[r] + bs;
        }
    }
}

extern "C" void kernel_launch(void* const* d_in, const int* in_sizes, int n_in,
                              void* d_out, int out_size, void* d_ws, size_t ws_size,
                              hipStream_t stream) {
    const float* x     = (const float*)d_in[0];
    const int*   erows = (const int*)d_in[1];
    const int*   ecols = (const int*)d_in[2];
    const float* evals = (const float*)d_in[3];
    const int*   erels = (const int*)d_in[4];
    const float* relc  = (const float*)d_in[5];
    const float* ck    = (const float*)d_in[6];
    const float* W     = (const float*)d_in[7];
    const float* bias  = (const float*)d_in[8];
    const float* gamma = (const float*)d_in[9];
    const float* beta  = (const float*)d_in[10];
    const float* mean  = (const float*)d_in[11];
    const float* var   = (const float*)d_in[12];
    float* out = (float*)d_out;

    char* wp = (char*)d_ws;
    auto alloc = [&](size_t bytes) {
        char* p = wp;
        wp += (bytes + 255) & ~(size_t)255;
        return (void*)p;
    };
    uint16_t* h      = (uint16_t*)alloc((size_t)N_PAD * FDIM * 2);       // 25.6 MB
    uint2* staging   = (uint2*)alloc((size_t)NBUCK * SCAP * 8);          // 23.2 MB
    uint2* rowrange  = (uint2*)alloc((size_t)N_PAD * 8);                 // 0.8 MB
    int* gcur        = (int*)alloc((size_t)NBUCK * 4);
    uint16_t* WT     = (uint16_t*)alloc(FDIM * FDIM * 2);
    if ((size_t)(wp - (char*)d_ws) > ws_size) return;

    hipMemsetAsync(gcur, 0, (size_t)NBUCK * 4, stream);
    pre_kernel<<<NBLK + 1 + HBLK, 512, 0, stream>>>(
        x, erows, ecols, evals, erels, relc, gamma, beta, mean, var, W,
        (uint2*)h, WT, gcur, staging);
    bucket_kernel<<<NBUCK, 256, 0, stream>>>(gcur, staging, rowrange);
    sg_kernel<<<NSG, 256, 0, stream>>>((const uint32_t*)h, rowrange, staging, ck,
                                       WT, bias, out);
}

// Round 2
// 259.894 us; speedup vs baseline: 1.1058x; 1.0415x over previous
//
#include <hip/hip_runtime.h>
#include <stdint.h>

#define N_NODES 100000
#define N_EDGES 1600000
#define FDIM 128
#define NREL 50
#define BN_EPS 1e-3f
#define N_PAD 100096
#define NBUCK 782          // ceil(N_NODES / 128)
#define EPB 8192           // edges per ingest block
#define NBLK 196           // ceil(N_EDGES / EPB)
#define HBLK 6250          // N*32 / 512  (BN float4 blocks)
#define LEDCAP 2816        // max edges per bucket (mean 2046, sigma ~45 -> 17 sigma headroom)
#define SLACK 384          // max pad per bucket: 128 rows * 3 (pad-to-4)
#define SCAP 3200          // bucket stride in entries = LEDCAP + SLACK, mult of 4
#define NSG 6250           // N_NODES / 16 rows per block (exact)

typedef short short8_t __attribute__((ext_vector_type(8)));
typedef float f32x4_t __attribute__((ext_vector_type(4)));

__device__ __forceinline__ uint32_t f2bf(float f) {
    union { float f; uint32_t u; } v; v.f = f;
    uint32_t u = v.u;
    return (u + 0x7FFFu + ((u >> 16) & 1u)) >> 16;   // RNE, inputs finite
}
__device__ __forceinline__ float bflo(uint32_t p) {
    union { uint32_t u; float f; } v; v.u = p << 16; return v.f;
}
__device__ __forceinline__ float bfhi(uint32_t p) {
    union { uint32_t u; float f; } v; v.u = p & 0xFFFF0000u; return v.f;
}

// ---- fused prologue:
//   blocks [0,NBLK)          : edge binning (LDS hist -> one global atomicAdd per
//                              bucket reserves space in fixed-stride region -> scatter)
//   block NBLK               : WT cast (bf16 transpose of dense kernel)
//   blocks (NBLK,NBLK+HBLK]  : BN h (bf16x2-packed), params L2-hot
__global__ __launch_bounds__(512) void pre_kernel(
        const float* __restrict__ x, const int* __restrict__ rows,
        const int* __restrict__ cols, const float* __restrict__ vals,
        const int* __restrict__ rels, const float* __restrict__ relc,
        const float* __restrict__ gamma, const float* __restrict__ beta,
        const float* __restrict__ mean, const float* __restrict__ var,
        const float* __restrict__ W,
        uint2* __restrict__ h, uint16_t* __restrict__ WT,
        int* __restrict__ gcur, uint2* __restrict__ staging) {
    __shared__ int lh[NBUCK];
    __shared__ float lrel[NREL];
    int b = blockIdx.x, t = threadIdx.x;
    if (b < NBLK) {
        if (t < NREL) lrel[t] = 1.0f / (relc[t] + 1.0f);
        for (int i = t; i < NBUCK; i += 512) lh[i] = 0;
        __syncthreads();
        int e0 = b * EPB, e1 = min(e0 + EPB, N_EDGES);
        for (int e = e0 + t; e < e1; e += 512)
            atomicAdd(&lh[rows[e] >> 7], 1);
        __syncthreads();
        for (int i = t; i < NBUCK; i += 512) {
            int c = lh[i];
            int base = c ? atomicAdd(&gcur[i], c) : 0;
            lh[i] = i * SCAP + base;           // absolute cursor into staging
        }
        __syncthreads();
        for (int e = e0 + t; e < e1; e += 512) {
            int r = rows[e];
            float w = vals[e] * lrel[rels[e]];
            int p = atomicAdd(&lh[r >> 7], 1);
            uint2 s;
            s.x = (uint32_t)cols[e] | ((uint32_t)(r & 127) << 20);  // col<2^17
            s.y = __float_as_uint(w);
            staging[p] = s;
        }
    } else if (b == NBLK) {
        for (int idx = t; idx < FDIM * FDIM; idx += 512) {
            int f = idx >> 7, k = idx & 127;
            WT[idx] = (uint16_t)f2bf(W[k * FDIM + f]);   // WT[f][k]
        }
    } else {
        int i4 = (b - NBLK - 1) * 512 + t;     // 0 .. N*32-1 exactly
        int cg = (i4 & 31) * 4;
        float4 xv = ((const float4*)x)[i4];
        float4 g4 = *(const float4*)(gamma + cg);
        float4 b4 = *(const float4*)(beta + cg);
        float4 m4 = *(const float4*)(mean + cg);
        float4 v4 = *(const float4*)(var + cg);
        float s0 = g4.x * rsqrtf(v4.x + BN_EPS);
        float s1 = g4.y * rsqrtf(v4.y + BN_EPS);
        float s2 = g4.z * rsqrtf(v4.z + BN_EPS);
        float s3 = g4.w * rsqrtf(v4.w + BN_EPS);
        uint2 o;
        o.x = f2bf((xv.x - m4.x) * s0 + b4.x) | (f2bf((xv.y - m4.y) * s1 + b4.y) << 16);
        o.y = f2bf((xv.z - m4.z) * s2 + b4.z) | (f2bf((xv.w - m4.w) * s3 + b4.w) << 16);
        h[i4] = o;
    }
}

// ---- per-bucket: LDS-buffered in-place rewrite of staging into padded per-row
//      layout (pad to 4 for the 4-wide dual-stream spmm loop) + rowrange ----
__global__ __launch_bounds__(256) void bucket_kernel(
        const int* __restrict__ gcur, uint2* __restrict__ staging,
        uint2* __restrict__ rowrange) {
    __shared__ uint2 led[LEDCAP];            // 22.5 KB edge buffer
    __shared__ int lh[128];
    __shared__ int sm[128];
    __shared__ int lcur[128];
    int b = blockIdx.x, r0 = b << 7, t = threadIdx.x;
    int nrows = min(128, N_NODES - r0);
    int cnt = min(gcur[b], LEDCAP);
    uint2* sg = staging + (size_t)b * SCAP;
    if (t < 128) lh[t] = 0;
    __syncthreads();
    for (int e = t; e < cnt; e += 256) {
        uint2 s = sg[e];
        led[e] = s;
        atomicAdd(&lh[(s.x >> 20) & 127], 1);
    }
    __syncthreads();
    int v = (t < 128) ? lh[t] : 0;
    int pv = (v + 3) & ~3;                   // pad each row to multiple of 4
    if (t < 128) sm[t] = pv;
    __syncthreads();
    for (int off = 1; off < 128; off <<= 1) {
        int xv = 0;
        if (t < 128 && t >= off) xv = sm[t - off];
        __syncthreads();
        if (t < 128) sm[t] += xv;
        __syncthreads();
    }
    int sbase = b * SCAP;
    int start = 0;
    if (t < 128) {
        start = sbase + sm[t] - pv;          // exclusive padded offset (mult of 4)
        lcur[t] = start;
        if (t < nrows) {
            uint2 rr; rr.x = (uint32_t)start; rr.y = (uint32_t)(start + pv);
            rowrange[r0 + t] = rr;
        }
    }
    __syncthreads();
    for (int e = t; e < cnt; e += 256) {
        uint2 s = led[e];
        int rl = (s.x >> 20) & 127;
        int p = atomicAdd(&lcur[rl], 1);
        uint2 o; o.x = s.x & 0xFFFFF; o.y = s.y;
        staging[p] = o;
    }
    // zero-weight pads: [start+v, start+pv) disjoint from reorder writes
    if (t < 128) {
        uint2 z; z.x = 0; z.y = 0;
        for (int k = v; k < pv; ++k) staging[start + k] = z;
    }
}

// ---- fused pull-SpMM + diag + GEMM.
//   block = 16 rows, 512 threads (8 waves); grid 6250 -> 24+ blocks/CU available.
//   Phase 1: wave owns 2 rows, DUAL edge streams in one loop (8 gathers in
//   flight), packs bf16 into bank-swizzled 4KB LDS tile.
//   Phase 2: wave w computes col-tile w (16 cols) of the 16x128 output. ----
__global__ __launch_bounds__(512, 8) void sg_kernel(
        const uint32_t* __restrict__ h, const uint2* __restrict__ rowrange,
        const uint2* __restrict__ scolw, const float* __restrict__ ck,
        const uint16_t* __restrict__ WT, const float* __restrict__ bias,
        float* __restrict__ out) {
    __shared__ uint32_t lp[16 * 64];         // 4 KB, word ^= (row&7)<<2 swizzle
    int wv = threadIdx.x >> 6;               // 0..7
    int lane = threadIdx.x & 63;
    int row0 = blockIdx.x * 16;
    int rA = row0 + wv * 2, rB = rA + 1;     // always < N_NODES (exact grid)

    uint2 ra = rowrange[rA];
    uint2 rb = rowrange[rB];
    int eA  = __builtin_amdgcn_readfirstlane((int)ra.x);
    int e1A = __builtin_amdgcn_readfirstlane((int)ra.y);
    int eB  = __builtin_amdgcn_readfirstlane((int)rb.x);
    int e1B = __builtin_amdgcn_readfirstlane((int)rb.y);
    uint32_t pA = h[(uint32_t)rA * 64u + lane];
    uint32_t pB = h[(uint32_t)rB * 64u + lane];
    float cA = ck[rA] + 1.0f, cB = ck[rB] + 1.0f;
    float axA = cA * bflo(pA), ayA = cA * bfhi(pA);
    float axB = cB * bflo(pB), ayB = cB * bfhi(pB);

    // dual-stream main loop: 4 edge-quads worth of loads + 8 gathers in flight
    while (eA < e1A && eB < e1B) {
        const uint4* pa = (const uint4*)(scolw + eA);   // 32B aligned
        const uint4* pb = (const uint4*)(scolw + eB);
        uint4 a0 = pa[0], a1 = pa[1];
        uint4 b0 = pb[0], b1 = pb[1];
        uint32_t qa0 = h[a0.x * 64u + lane];
        uint32_t qa1 = h[a0.z * 64u + lane];
        uint32_t qa2 = h[a1.x * 64u + lane];
        uint32_t qa3 = h[a1.z * 64u + lane];
        uint32_t qb0 = h[b0.x * 64u + lane];
        uint32_t qb1 = h[b0.z * 64u + lane];
        uint32_t qb2 = h[b1.x * 64u + lane];
        uint32_t qb3 = h[b1.z * 64u + lane];
        float wa0 = __uint_as_float(a0.y), wa1 = __uint_as_float(a0.w);
        float wa2 = __uint_as_float(a1.y), wa3 = __uint_as_float(a1.w);
        float wb0 = __uint_as_float(b0.y), wb1 = __uint_as_float(b0.w);
        float wb2 = __uint_as_float(b1.y), wb3 = __uint_as_float(b1.w);
        axA += wa0 * bflo(qa0); ayA += wa0 * bfhi(qa0);
        axA += wa1 * bflo(qa1); ayA += wa1 * bfhi(qa1);
        axA += wa2 * bflo(qa2); ayA += wa2 * bfhi(qa2);
        axA += wa3 * bflo(qa3); ayA += wa3 * bfhi(qa3);
        axB += wb0 * bflo(qb0); ayB += wb0 * bfhi(qb0);
        axB += wb1 * bflo(qb1); ayB += wb1 * bfhi(qb1);
        axB += wb2 * bflo(qb2); ayB += wb2 * bfhi(qb2);
        axB += wb3 * bflo(qb3); ayB += wb3 * bfhi(qb3);
        eA += 4; eB += 4;
    }
    while (eA < e1A) {
        const uint4* pa = (const uint4*)(scolw + eA);
        uint4 a0 = pa[0], a1 = pa[1];
        uint32_t qa0 = h[a0.x * 64u + lane];
        uint32_t qa1 = h[a0.z * 64u + lane];
        uint32_t qa2 = h[a1.x * 64u + lane];
        uint32_t qa3 = h[a1.z * 64u + lane];
        float wa0 = __uint_as_float(a0.y), wa1 = __uint_as_float(a0.w);
        float wa2 = __uint_as_float(a1.y), wa3 = __uint_as_float(a1.w);
        axA += wa0 * bflo(qa0); ayA += wa0 * bfhi(qa0);
        axA += wa1 * bflo(qa1); ayA += wa1 * bfhi(qa1);
        axA += wa2 * bflo(qa2); ayA += wa2 * bfhi(qa2);
        axA += wa3 * bflo(qa3); ayA += wa3 * bfhi(qa3);
        eA += 4;
    }
    while (eB < e1B) {
        const uint4* pb = (const uint4*)(scolw + eB);
        uint4 b0 = pb[0], b1 = pb[1];
        uint32_t qb0 = h[b0.x * 64u + lane];
        uint32_t qb1 = h[b0.z * 64u + lane];
        uint32_t qb2 = h[b1.x * 64u + lane];
        uint32_t qb3 = h[b1.z * 64u + lane];
        float wb0 = __uint_as_float(b0.y), wb1 = __uint_as_float(b0.w);
        float wb2 = __uint_as_float(b1.y), wb3 = __uint_as_float(b1.w);
        axB += wb0 * bflo(qb0); ayB += wb0 * bfhi(qb0);
        axB += wb1 * bflo(qb1); ayB += wb1 * bfhi(qb1);
        axB += wb2 * bflo(qb2); ayB += wb2 * bfhi(qb2);
        axB += wb3 * bflo(qb3); ayB += wb3 * bfhi(qb3);
        eB += 4;
    }
    int rlA = wv * 2, rlB = rlA + 1;
    lp[rlA * 64 + (lane ^ ((rlA & 7) << 2))] = f2bf(axA) | (f2bf(ayA) << 16);
    lp[rlB * 64 + (lane ^ ((rlB & 7) << 2))] = f2bf(axB) | (f2bf(ayB) << 16);
    __syncthreads();

    // phase 2: wave wv -> col-tile wv (cols wv*16 .. +15), rows row0..row0+15
    int m = lane & 15, q = lane >> 4;
    short8_t a[4];
#pragma unroll
    for (int t = 0; t < 4; ++t) {
        int w0 = (q * 4 + t * 16) ^ ((m & 7) << 2);
        a[t] = *(const short8_t*)&lp[m * 64 + w0];
    }
    int col0 = wv * 16;
    const uint16_t* brow = WT + (size_t)(col0 + m) * FDIM + q * 8;
    f32x4_t acc = {0.f, 0.f, 0.f, 0.f};
#pragma unroll
    for (int t = 0; t < 4; ++t) {
        short8_t bb = *(const short8_t*)(brow + t * 32);
        acc = __builtin_amdgcn_mfma_f32_16x16x32_bf16(a[t], bb, acc, 0, 0, 0);
    }
    float bs = bias[col0 + m];
#pragma unroll
    for (int r = 0; r < 4; ++r)
        out[(size_t)(row0 + q * 4 + r) * FDIM + col0 + m] = acc[r] + bs;
}

extern "C" void kernel_launch(void* const* d_in, const int* in_sizes, int n_in,
                              void* d_out, int out_size, void* d_ws, size_t ws_size,
                              hipStream_t stream) {
    const float* x     = (const float*)d_in[0];
    const int*   erows = (const int*)d_in[1];
    const int*   ecols = (const int*)d_in[2];
    const float* evals = (const float*)d_in[3];
    const int*   erels = (const int*)d_in[4];
    const float* relc  = (const float*)d_in[5];
    const float* ck    = (const float*)d_in[6];
    const float* W     = (const float*)d_in[7];
    const float* bias  = (const float*)d_in[8];
    const float* gamma = (const float*)d_in[9];
    const float* beta  = (const float*)d_in[10];
    const float* mean  = (const float*)d_in[11];
    const float* var   = (const float*)d_in[12];
    float* out = (float*)d_out;

    char* wp = (char*)d_ws;
    auto alloc = [&](size_t bytes) {
        char* p = wp;
        wp += (bytes + 255) & ~(size_t)255;
        return (void*)p;
    };
    uint16_t* h      = (uint16_t*)alloc((size_t)N_PAD * FDIM * 2);       // 25.6 MB
    uint2* staging   = (uint2*)alloc((size_t)NBUCK * SCAP * 8);          // 20.0 MB
    uint2* rowrange  = (uint2*)alloc((size_t)N_PAD * 8);                 // 0.8 MB
    int* gcur        = (int*)alloc((size_t)NBUCK * 4);
    uint16_t* WT     = (uint16_t*)alloc(FDIM * FDIM * 2);
    if ((size_t)(wp - (char*)d_ws) > ws_size) return;

    hipMemsetAsync(gcur, 0, (size_t)NBUCK * 4, stream);
    pre_kernel<<<NBLK + 1 + HBLK, 512, 0, stream>>>(
        x, erows, ecols, evals, erels, relc, gamma, beta, mean, var, W,
        (uint2*)h, WT, gcur, staging);
    bucket_kernel<<<NBUCK, 256, 0, stream>>>(gcur, staging, rowrange);
    sg_kernel<<<NSG, 512, 0, stream>>>((const uint32_t*)h, rowrange, staging, ck,
                                       WT, bias, out);
}